// Round 6
// baseline (807.837 us; speedup 1.0000x reference)
//
#include <hip/hip_runtime.h>
#include <math.h>

#define B 8
#define C 128
#define H 160
#define W 160
#define HW 25600
#define WP 162   // padded width/height (pad=1 ring of zeros)

typedef short bf16x8 __attribute__((ext_vector_type(8)));
typedef float f32x4  __attribute__((ext_vector_type(4)));

__device__ __forceinline__ unsigned short f2bf(float x) {  // RNE
    union { float f; unsigned u; } v; v.f = x;
    unsigned r = v.u + 0x7fff + ((v.u >> 16) & 1);
    return (unsigned short)(r >> 16);
}
__device__ __forceinline__ float bf2f(unsigned short h) {
    union { unsigned u; float f; } v; v.u = ((unsigned)h) << 16;
    return v.f;
}

// async global->LDS, 16 B per lane; LDS dest = uniform base + lane*16
__device__ __forceinline__ void gload16(const unsigned short* g, unsigned short* l) {
    __builtin_amdgcn_global_load_lds(
        (const __attribute__((address_space(1))) void*)g,
        (__attribute__((address_space(3))) void*)l, 16, 0, 0);
}

// Activation layout ("chunk-pair interleaved", per padded pixel):
//   addr(px, ch, plane) = px*(2*C) + (ch>>5)*64 + plane*32 + (ch&31)

// ---------------- weight repack ----------------
// R6: W layout is now lane-coalesced for direct global->VGPR streaming:
//   dst[(tap*NKC + kc)*(COUT/16) + cb][lane][8]  with lane = q*16 + m,
//   co = cb*16 + m, granule q of the kc-chunk. A wave's (tap,kc,cb) read is
//   one contiguous 1-KB line set (16 B/lane).
__global__ void k_repack(const float* __restrict__ w1, const float* __restrict__ w2,
                         const float* __restrict__ w3, const float* __restrict__ dw,
                         const float* __restrict__ cw,
                         unsigned short* __restrict__ wpk1h, unsigned short* __restrict__ wpk1l,
                         unsigned short* __restrict__ wpk2h, unsigned short* __restrict__ wpk2l,
                         unsigned short* __restrict__ wpk3h, unsigned short* __restrict__ wpk3l,
                         float* __restrict__ wHT) {
    int idx = blockIdx.x * 256 + threadIdx.x;
    if (idx < 73728) {  // w1: COUT=128, CIN=64 (ci 0..49 real), NKC=2
        int t = idx / 8192; int r = idx % 8192; int co = r / 64; int ci = r % 64;
        float v = (ci < 50) ? w1[(co * 50 + ci) * 9 + t] : 0.f;
        unsigned short h = f2bf(v);
        int dst = ((t * 2 + (ci >> 5)) * 8 + (co >> 4)) * 512
                + (((ci >> 3) & 3) * 16 + (co & 15)) * 8 + (ci & 7);
        wpk1h[dst] = h; wpk1l[dst] = f2bf(v - bf2f(h));
        return;
    }
    idx -= 73728;
    if (idx < 73728) {  // w2: COUT=64, CIN=128, NKC=4
        int t = idx / 8192; int r = idx % 8192; int co = r / 128; int ci = r % 128;
        float v = w2[(co * 128 + ci) * 9 + t];
        unsigned short h = f2bf(v);
        int dst = ((t * 4 + (ci >> 5)) * 4 + (co >> 4)) * 512
                + (((ci >> 3) & 3) * 16 + (co & 15)) * 8 + (ci & 7);
        wpk2h[dst] = h; wpk2l[dst] = f2bf(v - bf2f(h));
        return;
    }
    idx -= 73728;
    if (idx < 18432) {  // w3: COUT=32, CIN=64, NKC=2
        int t = idx / 2048; int r = idx % 2048; int co = r / 64; int ci = r % 64;
        float v = w3[(co * 64 + ci) * 9 + t];
        unsigned short h = f2bf(v);
        int dst = ((t * 2 + (ci >> 5)) * 2 + (co >> 4)) * 512
                + (((ci >> 3) & 3) * 16 + (co & 15)) * 8 + (ci & 7);
        wpk3h[dst] = h; wpk3l[dst] = f2bf(v - bf2f(h));
        return;
    }
    idx -= 18432;
    if (idx < 2400) {   // heads (fp32): wHT[ci][k][3]: 0,1=disp 2=conf
        int ci = idx / 75; int rem = idx % 75; int k = rem / 3; int co = rem % 3;
        wHT[idx] = (co < 2) ? dw[(co * 32 + ci) * 25 + k] : cw[ci * 25 + k];
    }
}

// ---------------- zero the pad rings of xin (2C=128) and x1 (2C=256) ----------------
__global__ void k_zeropad(unsigned short* __restrict__ xin, unsigned short* __restrict__ x1) {
    int idx = blockIdx.x * 256 + threadIdx.x;
    unsigned short* p; int C2;
    if (idx < 82432) { p = xin; C2 = 128; }
    else {
        idx -= 82432;
        if (idx >= 164864) return;
        p = x1; C2 = 256;
    }
    int chunks = C2 / 8;
    int percnt = 644 * chunks;
    int img = idx / percnt;
    int r = idx % percnt;
    int rp = r / chunks; int ch = r % chunks;
    int yy, xx;
    if (rp < 162)      { yy = 0;   xx = rp; }
    else if (rp < 324) { yy = 161; xx = rp - 162; }
    else { int s = rp - 324; yy = 1 + (s >> 1); xx = (s & 1) ? 161 : 0; }
    size_t off = ((size_t)(img * WP + yy) * WP + xx) * C2 + ch * 8;
    bf16x8 z = {0, 0, 0, 0, 0, 0, 0, 0};
    *(bf16x8*)&p[off] = z;
}

// ---------------- deconv upsample (stride 2, pad 1, k=4) ----------------
// NOTE: must run AFTER k_corr — k_corr's packed epilogue writes each pixel's
// full 256-B block (channel 49 slots zeroed); this kernel then fills conf
// into channel 49.
__global__ void k_upsample(const float* __restrict__ flow, const float* __restrict__ conf,
                           const float* __restrict__ up_flow_w, const float* __restrict__ up_conf_w,
                           float* __restrict__ flow_up, unsigned short* __restrict__ xin) {
    int idx = blockIdx.x * 256 + threadIdx.x;
    if (idx >= B * 3 * HW) return;
    int x = idx % W;
    int y = (idx / W) % H;
    int ch = (idx / HW) % 3;
    int b = idx / (3 * HW);
    const float* in;
    const float* w;
    if (ch < 2) { in = flow + (size_t)(b * 2 + ch) * 6400; w = up_flow_w + ch * 16; }
    else        { in = conf + (size_t)b * 6400;            w = up_conf_w; }
    float acc = 0.f;
#pragma unroll
    for (int dy = 0; dy < 4; ++dy) {
        int tny = y + 1 - dy;
        if (tny < 0 || (tny & 1)) continue;
        int iy = tny >> 1;
        if (iy >= 80) continue;
#pragma unroll
        for (int dx = 0; dx < 4; ++dx) {
            int tnx = x + 1 - dx;
            if (tnx < 0 || (tnx & 1)) continue;
            int ix = tnx >> 1;
            if (ix >= 80) continue;
            acc += in[iy * 80 + ix] * w[dy * 4 + dx];
        }
    }
    if (ch < 2) flow_up[(size_t)(b * 2 + ch) * HW + y * W + x] = acc;
    else {
        // conf is channel 49: chunk 1, within 17
        size_t off = ((size_t)(b * WP + y + 1) * WP + (x + 1)) * 128 + 64 + 17;
        unsigned short h = f2bf(acc);
        xin[off] = h;
        xin[off + 32] = f2bf(acc - bf2f(h));
    }
}

// ---------------- dilated self-correlation (PATCH=7, DIL=2) ----------------
// 4-channel f32x4 staging (ds_read_b128 taps) + packed 16B epilogue stores.
// Channel 49 slots written ZERO here (conf lands there later via k_upsample).
__global__ __launch_bounds__(256, 4) void k_corr(const float* __restrict__ feats,
                                                 unsigned short* __restrict__ xin) {
    const int bid = blockIdx.x;
    const int b = bid & 7;
    const int t = bid >> 3;           // 0..99
    const int x0 = (t % 5) * 32;
    const int y0 = (t / 5) * 8;
    const int tid = threadIdx.x;
    const int tx = tid & 31;
    const int ty = tid >> 5;          // 0..7
    __shared__ f32x4 sh[2][880];      // 20 rows x 44 cols x 4 ch, double-buffered (28.2 KB)
    float acc[49];
#pragma unroll
    for (int i = 0; i < 49; ++i) acc[i] = 0.f;

    int soff[4]; bool sval[4];
#pragma unroll
    for (int s = 0; s < 4; ++s) {
        int i = tid + s * 256;
        int r = i / 44, cc = i % 44;
        int gy = y0 + r - 6, gx = x0 + cc - 6;
        sval[s] = (i < 880) && gy >= 0 && gy < H && gx >= 0 && gx < W;
        soff[s] = sval[s] ? (gy * W + gx) : 0;
    }
    const float* f = feats + (size_t)b * 2 * C * HW;  // feats[b, 0]
    f32x4 pre[4];
#pragma unroll
    for (int s = 0; s < 4; ++s)
#pragma unroll
        for (int c4 = 0; c4 < 4; ++c4)
            pre[s][c4] = sval[s] ? f[(size_t)c4 * HW + soff[s]] : 0.f;

    for (int cg = 0; cg < 32; ++cg) {          // channel groups of 4
        f32x4* buf = sh[cg & 1];
#pragma unroll
        for (int s = 0; s < 4; ++s) {
            int i = tid + s * 256;
            if (i < 880) buf[i] = pre[s];
        }
        if (cg < 31) {
            const float* fn = f + (size_t)(cg + 1) * 4 * HW;
#pragma unroll
            for (int s = 0; s < 4; ++s)
#pragma unroll
                for (int c4 = 0; c4 < 4; ++c4)
                    pre[s][c4] = sval[s] ? fn[(size_t)c4 * HW + soff[s]] : 0.f;
        }
        __syncthreads();
        f32x4 ctr = buf[(ty + 6) * 44 + tx + 6];
#pragma unroll
        for (int dy = 0; dy < 7; ++dy) {
            const f32x4* row = &buf[(ty + 2 * dy) * 44 + tx];
#pragma unroll
            for (int dx = 0; dx < 7; ++dx) {
                f32x4 rv = row[2 * dx];
                float a = acc[dy * 7 + dx];
                a += ctr[0] * rv[0];   // strictly channel-sequential
                a += ctr[1] * rv[1];
                a += ctr[2] * rv[2];
                a += ctr[3] * rv[3];
                acc[dy * 7 + dx] = a;
            }
        }
        __syncthreads();
    }
    // epilogue: pack the pixel's 256-B block (hi|lo chunk-pair layout) and
    // store as 16 x dwordx4. Short j of 128: chunk=j>>6, plane=(j>>5)&1,
    // ch = chunk*32 + (j&31); ch>=49 -> 0 (49=conf, filled by k_upsample after).
    size_t pbase = ((size_t)(b * WP + y0 + ty + 1) * WP + (x0 + tx + 1)) * 128;
#pragma unroll
    for (int g = 0; g < 16; ++g) {
        bf16x8 pk;
#pragma unroll
        for (int e = 0; e < 8; ++e) {
            const int ch = ((g >> 3) * 32) + ((g & 3) * 8) + e;
            const int plane = (g >> 2) & 1;
            unsigned short os = 0;
            if (ch < 49) {
                float v = acc[ch];
                v = (v > 0.f) ? v : 0.1f * v;   // leaky_relu(0.1)
                v *= 0.0078125f;                // / 128
                unsigned short h = f2bf(v);
                os = plane ? f2bf(v - bf2f(h)) : h;
            }
            pk[e] = (short)os;
        }
        *(bf16x8*)&xin[pbase + g * 8] = pk;
    }
}

// ---------------- split-bf16 MFMA 3x3 conv + bias + leaky_relu ----------------
// R6: LDS holds ONLY the A-tile, shrunk to 4 rows x 160 interior px x 128 B =
// exactly 81,920 B -> TWO blocks/CU co-resident (one block's compute hides the
// other's staging drain; R3's 156-KB A+W footprint forced 1 block/CU and the
// per-kc vmcnt(0) drain was ~50% of the kernel). W is streamed global->VGPR in
// the lane-coalesced repack layout (1-KB wave reads, per-tap 8-KB window stays
// L1-hot across the 8 resident waves), double-buffered across taps.
// The two dropped zero-pad columns are reproduced exactly: the single affected
// fragment per edge tap is zeroed (oobL/oobR), so accumulation is bit-identical.
template<int CIN, int COUT, int COB, int NCO, int OUTF>
__global__ __launch_bounds__(256, 2) void k_convM(
    const unsigned short* __restrict__ in,
    const unsigned short* __restrict__ w_hi,  const unsigned short* __restrict__ w_lo,
    const float* __restrict__ bias,
    unsigned short* __restrict__ out_pk, float* __restrict__ out_f) {
    constexpr int NT = COB / 16;
    constexpr int NKC = CIN / 32;
    constexpr int CI2 = 2 * CIN;
    constexpr int NCB = COUT / 16;           // co-blocks in W layout
    __shared__ __align__(128) unsigned short At[4 * 160 * 64];  // 81,920 B exactly

    const int bid = blockIdx.x;
    const int b = bid & 7;
    const int t = bid >> 3;
    const int co0 = (t % NCO) * COB;
    const int cb0 = co0 >> 4;
    const int ybx = t / NCO;
    const int wave = threadIdx.x >> 6;
    const int lane = threadIdx.x & 63;
    const int rw = wave >> 1;              // row within block: 0/1
    const int x0w = (wave & 1) * 80;
    const int y = ybx * 2 + rw;            // interior row 0..159
    const int m = lane & 15, q = lane >> 4;
    const int arow0 = b * WP + 2 * ybx;    // padded row base of the A-tile
    const bool oobL = (x0w == 0) && (m == 0);    // dx=0, mt=0 reads pad col
    const bool oobR = (x0w == 80) && (m == 15);  // dx=2, mt=4 reads pad col
    const bf16x8 zf = {0, 0, 0, 0, 0, 0, 0, 0};

    f32x4 acc[5][NT];
#pragma unroll
    for (int mt = 0; mt < 5; ++mt)
#pragma unroll
        for (int nt = 0; nt < NT; ++nt) acc[mt][nt] = (f32x4){0.f, 0.f, 0.f, 0.f};

    bf16x8 ah[2][5], al[2][5], bh[2][NT], bl[2][NT];

    // A-fragment loader: tile index ti = x + dx - 1 in [0,159]; OOB ti maps to
    // a clamped address and the frag is zeroed (pad column semantics).
    auto lda = [&](int dy, int dx, bf16x8* dsth, bf16x8* dstl) {
        const int tib = x0w + m + dx - 1;
#pragma unroll
        for (int mt = 0; mt < 5; ++mt) {
            int ti = tib + mt * 16;
            ti = ti < 0 ? 0 : (ti > 159 ? 159 : ti);
            const int pl = (rw + dy) * 160 + ti;
            const int g16 = (pl << 3) ^ (pl & 7) ^ q;
            dsth[mt] = *(const bf16x8*)&At[g16 * 8];
            dstl[mt] = *(const bf16x8*)&At[(g16 ^ 4) * 8];
        }
        if (dx == 0 && oobL) { dsth[0] = zf; dstl[0] = zf; }
        if (dx == 2 && oobR) { dsth[4] = zf; dstl[4] = zf; }
    };

    for (int kc = 0; kc < NKC; ++kc) {
        __syncthreads();   // all waves done reading prev kc's LDS

        // ---- stage A-tile: 80 chunks of 1 KB, 20 per wave ----
#pragma unroll
        for (int k = 0; k < 20; ++k) {
            int c = k * 4 + wave;
            int ga = c * 64 + lane;          // 16-B granule id
            int pl = ga >> 3;                // tile pixel (row*160 + px)
            int r  = pl / 160;
            int px = pl - r * 160;
            int slot = (ga & 7) ^ (pl & 7);  // inverse XOR swizzle on SOURCE
            const unsigned short* src =
                in + ((size_t)(arow0 + r) * WP + (px + 1)) * CI2 + kc * 64 + slot * 8;
            gload16(src, At + c * 512);
        }
        // ---- W tap 0 (global -> regs, coalesced 16 B/lane) ----
#pragma unroll
        for (int nt = 0; nt < NT; ++nt) {
            const int wb = ((0 * NKC + kc) * NCB + cb0 + nt) * 512 + lane * 8;
            bh[0][nt] = *(const bf16x8*)&w_hi[wb];
            bl[0][nt] = *(const bf16x8*)&w_lo[wb];
        }
        asm volatile("s_waitcnt vmcnt(0)" ::: "memory");
        __syncthreads();   // LDS tile visible to all waves

        lda(0, 0, ah[0], al[0]);   // tap 0 A frags

#pragma unroll
        for (int tap = 0; tap < 9; ++tap) {
            const int cur = tap & 1, nxt = cur ^ 1;
            if (tap < 8) {   // prefetch tap+1: A from LDS, W from global
                const int tap1 = tap + 1;
                lda(tap1 / 3, tap1 % 3, ah[nxt], al[nxt]);
#pragma unroll
                for (int nt = 0; nt < NT; ++nt) {
                    const int wb = ((tap1 * NKC + kc) * NCB + cb0 + nt) * 512 + lane * 8;
                    bh[nxt][nt] = *(const bf16x8*)&w_hi[wb];
                    bl[nxt][nt] = *(const bf16x8*)&w_lo[wb];
                }
            }
#pragma unroll
            for (int nt = 0; nt < NT; ++nt) {
#pragma unroll
                for (int mt = 0; mt < 5; ++mt) {
                    acc[mt][nt] = __builtin_amdgcn_mfma_f32_16x16x32_bf16(ah[cur][mt], bh[cur][nt], acc[mt][nt], 0, 0, 0);
                    acc[mt][nt] = __builtin_amdgcn_mfma_f32_16x16x32_bf16(ah[cur][mt], bl[cur][nt], acc[mt][nt], 0, 0, 0);
                    acc[mt][nt] = __builtin_amdgcn_mfma_f32_16x16x32_bf16(al[cur][mt], bh[cur][nt], acc[mt][nt], 0, 0, 0);
                }
            }
        }
    }
    // epilogue: D col = lane&15 = co, D row = q*4+r = pixel within m-tile
#pragma unroll
    for (int nt = 0; nt < NT; ++nt) {
        const int co = co0 + nt * 16 + m;
        const float bv = bias[co];
#pragma unroll
        for (int mt = 0; mt < 5; ++mt) {
#pragma unroll
            for (int r = 0; r < 4; ++r) {
                float v = acc[mt][nt][r] + bv;
                v = (v > 0.f) ? v : 0.1f * v;
                const int x = x0w + mt * 16 + q * 4 + r;
                if (OUTF) {
                    out_f[((size_t)(b * COUT + co)) * HW + y * W + x] = v;
                } else {
                    const size_t off = ((size_t)(b * WP + y + 1) * WP + (x + 1)) * (2 * COUT)
                                     + ((co >> 5) * 64) + (co & 31);
                    unsigned short h = f2bf(v);
                    out_pk[off] = h;
                    out_pk[off + 32] = f2bf(v - bf2f(h));
                }
            }
        }
    }
}

// ---------------- fused heads (5x5 convs) + warp + sigmoid ----------------
__global__ __launch_bounds__(256) void k_head(const float* __restrict__ x3,
                                              const float* __restrict__ wHT,
                                              const float* __restrict__ disp_b,
                                              const float* __restrict__ conf_b,
                                              const float* __restrict__ flow_up,
                                              float* __restrict__ out) {
    const int bid = blockIdx.x;
    const int b = bid & 7;
    const int t = bid >> 3;           // 0..99
    const int x0 = (t % 10) * 16, y0 = (t / 10) * 16;
    const int tx = threadIdx.x & 15, ty = threadIdx.x >> 4;
    const int tid = threadIdx.x;
    __shared__ float sh[2 * 400];  // 2 channels x 20x20
    float a0 = 0.f, a1 = 0.f, a2 = 0.f;
    const float* xb = x3 + (size_t)(b * 32) * HW;
    for (int ci = 0; ci < 32; ci += 2) {
        __syncthreads();
        for (int i = tid; i < 800; i += 256) {
            int cc = i / 400;
            int rem = i - cc * 400;
            int r = rem / 20, c2 = rem % 20;
            int gy = y0 + r - 2, gx = x0 + c2 - 2;
            float v = 0.f;
            if (gy >= 0 && gy < H && gx >= 0 && gx < W)
                v = xb[(size_t)(ci + cc) * HW + gy * W + gx];
            sh[i] = v;
        }
        __syncthreads();
#pragma unroll
        for (int cc = 0; cc < 2; ++cc) {
            const float* t2 = sh + cc * 400;
            const float* wp = wHT + (size_t)(ci + cc) * 75;
#pragma unroll
            for (int k = 0; k < 25; ++k) {
                float v = t2[(ty + k / 5) * 20 + tx + (k % 5)];
                a0 += v * wp[k * 3 + 0];
                a1 += v * wp[k * 3 + 1];
                a2 += v * wp[k * 3 + 2];
            }
        }
    }
    const int gx = x0 + tx, gy = y0 + ty;
    float d0 = a0 + disp_b[0];
    float d1 = a1 + disp_b[1];
    float cf = a2 + conf_b[0];
    cf = 1.f / (1.f + expf(-cf));

    float px = (float)gx + d0, py = (float)gy + d1;
    float x0f = floorf(px), y0f = floorf(py);
    float wx1 = px - x0f, wx0 = 1.f - wx1;
    float wy1 = py - y0f, wy0 = 1.f - wy1;
    const float* f0 = flow_up + (size_t)(b * 2) * HW;
    const float* f1 = f0 + HW;

    float m00, m01, m10, m11;
    float a00, a01, a10, a11;
    float b00, b01, b10, b11;
    auto corner = [&](float xf, float yf, float& m, float& c0, float& c1) {
        bool valid = (xf >= 0.f) && (xf <= (float)(W - 1)) && (yf >= 0.f) && (yf <= (float)(H - 1));
        m = valid ? 1.f : 0.f;
        if (valid) {
            int xi = (int)xf, yi = (int)yf;
            int o = yi * W + xi;
            c0 = f0[o]; c1 = f1[o];
        } else { c0 = 0.f; c1 = 0.f; }
    };
    corner(x0f,       y0f,       m00, a00, b00);
    corner(x0f + 1.f, y0f,       m01, a01, b01);
    corner(x0f,       y0f + 1.f, m10, a10, b10);
    corner(x0f + 1.f, y0f + 1.f, m11, a11, b11);

    float o0 = wy0 * (wx0 * a00 + wx1 * a01) + wy1 * (wx0 * a10 + wx1 * a11);
    float o1 = wy0 * (wx0 * b00 + wx1 * b01) + wy1 * (wx0 * b10 + wx1 * b11);
    float msk = wy0 * (wx0 * m00 + wx1 * m01) + wy1 * (wx0 * m10 + wx1 * m11);
    float mask = (msk >= 1.f) ? 1.f : 0.f;

    int o = gy * W + gx;
    out[(size_t)(b * 2 + 0) * HW + o] = o0 * mask;
    out[(size_t)(b * 2 + 1) * HW + o] = o1 * mask;
    out[(size_t)B * 2 * HW + (size_t)b * HW + o] = cf;
}

extern "C" void kernel_launch(void* const* d_in, const int* in_sizes, int n_in,
                              void* d_out, int out_size, void* d_ws, size_t ws_size,
                              hipStream_t stream) {
    const float* feats     = (const float*)d_in[0];
    const float* flow      = (const float*)d_in[1];
    const float* conf      = (const float*)d_in[2];
    const float* up_conf_w = (const float*)d_in[3];
    const float* up_flow_w = (const float*)d_in[4];
    const float* w1        = (const float*)d_in[5];
    const float* b1        = (const float*)d_in[6];
    const float* w2        = (const float*)d_in[7];
    const float* b2        = (const float*)d_in[8];
    const float* w3        = (const float*)d_in[9];
    const float* b3        = (const float*)d_in[10];
    const float* disp_w    = (const float*)d_in[11];
    const float* disp_b    = (const float*)d_in[12];
    const float* conf_w    = (const float*)d_in[13];
    const float* conf_b    = (const float*)d_in[14];
    float* out = (float*)d_out;

    // workspace layout (bytes)
    char* p = (char*)d_ws;
    const size_t SZ_XIN = (size_t)B * WP * WP * 128 * 2;   // 53,747,712 (hi|lo interleaved)
    const size_t SZ_X1  = (size_t)B * WP * WP * 256 * 2;   // 107,495,424
    unsigned short* xin = (unsigned short*)p;
    unsigned short* x1  = (unsigned short*)(p + SZ_XIN);
    char* p2 = p + SZ_XIN + SZ_X1;
    float* flow_up = (float*)p2;                 // 1,638,400 B
    float* wHT     = (float*)(p2 + 1638400);     // 9,600 B
    unsigned short* wpk1h = (unsigned short*)(p2 + 1648000);
    unsigned short* wpk1l = wpk1h + 73728;
    unsigned short* wpk2h = wpk1l + 73728;
    unsigned short* wpk2l = wpk2h + 73728;
    unsigned short* wpk3h = wpk2l + 73728;
    unsigned short* wpk3l = wpk3h + 18432;
    // aliases: x2 reuses xin (same geometry 2C=128, ring stays zero); x3 reuses x1
    unsigned short* x2 = xin;
    float* x3 = (float*)x1;   // 26.2 MB <= SZ_X1, x1 dead after conv2

    k_repack<<<658, 256, 0, stream>>>(w1, w2, w3, disp_w, conf_w,
                                      wpk1h, wpk1l, wpk2h, wpk2l, wpk3h, wpk3l, wHT);
    k_zeropad<<<966, 256, 0, stream>>>(xin, x1);
    // ORDER: k_corr writes each pixel's full 256-B block (ch 49 zeroed);
    // k_upsample then fills conf into ch 49. Same stream -> sequential.
    k_corr<<<800, 256, 0, stream>>>(feats, xin);
    k_upsample<<<(B * 3 * HW + 255) / 256, 256, 0, stream>>>(flow, conf, up_flow_w, up_conf_w,
                                                             flow_up, xin);
    k_convM<64, 128, 64, 2, 0><<<1280, 256, 0, stream>>>(xin, wpk1h, wpk1l, b1, x1, nullptr);
    k_convM<128, 64, 64, 1, 0><<<640, 256, 0, stream>>>(x1, wpk2h, wpk2l, b2, x2, nullptr);
    k_convM<64, 32, 32, 1, 1><<<640, 256, 0, stream>>>(x2, wpk3h, wpk3l, b3, nullptr, x3);
    k_head<<<800, 256, 0, stream>>>(x3, wHT, disp_b, conf_b, flow_up, out);
}

// Round 7
// 678.840 us; speedup vs baseline: 1.1900x; 1.1900x over previous
//
#include <hip/hip_runtime.h>
#include <math.h>

#define B 8
#define C 128
#define H 160
#define W 160
#define HW 25600
#define WP 162   // padded width/height (pad=1 ring of zeros)

typedef short bf16x8 __attribute__((ext_vector_type(8)));
typedef float f32x4  __attribute__((ext_vector_type(4)));

__device__ __forceinline__ unsigned short f2bf(float x) {  // RNE
    union { float f; unsigned u; } v; v.f = x;
    unsigned r = v.u + 0x7fff + ((v.u >> 16) & 1);
    return (unsigned short)(r >> 16);
}
__device__ __forceinline__ float bf2f(unsigned short h) {
    union { unsigned u; float f; } v; v.u = ((unsigned)h) << 16;
    return v.f;
}

// async global->LDS, 16 B per lane; LDS dest = uniform base + lane*16
__device__ __forceinline__ void gload16(const unsigned short* g, unsigned short* l) {
    __builtin_amdgcn_global_load_lds(
        (const __attribute__((address_space(1))) void*)g,
        (__attribute__((address_space(3))) void*)l, 16, 0, 0);
}

// Activation layout ("chunk-pair interleaved", per padded pixel):
//   addr(px, ch, plane) = px*(2*C) + (ch>>5)*64 + plane*32 + (ch&31)

// ---------------- weight repack: split-bf16 [tap][co][ci] (R3 layout) ----------------
__global__ void k_repack(const float* __restrict__ w1, const float* __restrict__ w2,
                         const float* __restrict__ w3, const float* __restrict__ dw,
                         const float* __restrict__ cw,
                         unsigned short* __restrict__ wpk1h, unsigned short* __restrict__ wpk1l,
                         unsigned short* __restrict__ wpk2h, unsigned short* __restrict__ wpk2l,
                         unsigned short* __restrict__ wpk3h, unsigned short* __restrict__ wpk3l,
                         float* __restrict__ wHT) {
    int idx = blockIdx.x * 256 + threadIdx.x;
    if (idx < 73728) {  // w1: [t][co=128][ci=64]  (ci 0..49 real, 50..63 zero)
        int t = idx / 8192; int r = idx % 8192; int co = r / 64; int ci = r % 64;
        float v = (ci < 50) ? w1[(co * 50 + ci) * 9 + t] : 0.f;
        unsigned short h = f2bf(v);
        wpk1h[idx] = h; wpk1l[idx] = f2bf(v - bf2f(h));
        return;
    }
    idx -= 73728;
    if (idx < 73728) {  // w2: [t][co=64][ci=128]
        int t = idx / 8192; int r = idx % 8192; int co = r / 128; int ci = r % 128;
        float v = w2[(co * 128 + ci) * 9 + t];
        unsigned short h = f2bf(v);
        wpk2h[idx] = h; wpk2l[idx] = f2bf(v - bf2f(h));
        return;
    }
    idx -= 73728;
    if (idx < 18432) {  // w3: [t][co=32][ci=64]
        int t = idx / 2048; int r = idx % 2048; int co = r / 64; int ci = r % 64;
        float v = w3[(co * 64 + ci) * 9 + t];
        unsigned short h = f2bf(v);
        wpk3h[idx] = h; wpk3l[idx] = f2bf(v - bf2f(h));
        return;
    }
    idx -= 18432;
    if (idx < 2400) {   // heads (fp32): wHT[ci][k][3]: 0,1=disp 2=conf
        int ci = idx / 75; int rem = idx % 75; int k = rem / 3; int co = rem % 3;
        wHT[idx] = (co < 2) ? dw[(co * 32 + ci) * 25 + k] : cw[ci * 25 + k];
    }
}

// ---------------- zero the pad rings of xin (2C=128) and x1 (2C=256) ----------------
__global__ void k_zeropad(unsigned short* __restrict__ xin, unsigned short* __restrict__ x1) {
    int idx = blockIdx.x * 256 + threadIdx.x;
    unsigned short* p; int C2;
    if (idx < 82432) { p = xin; C2 = 128; }
    else {
        idx -= 82432;
        if (idx >= 164864) return;
        p = x1; C2 = 256;
    }
    int chunks = C2 / 8;
    int percnt = 644 * chunks;
    int img = idx / percnt;
    int r = idx % percnt;
    int rp = r / chunks; int ch = r % chunks;
    int yy, xx;
    if (rp < 162)      { yy = 0;   xx = rp; }
    else if (rp < 324) { yy = 161; xx = rp - 162; }
    else { int s = rp - 324; yy = 1 + (s >> 1); xx = (s & 1) ? 161 : 0; }
    size_t off = ((size_t)(img * WP + yy) * WP + xx) * C2 + ch * 8;
    bf16x8 z = {0, 0, 0, 0, 0, 0, 0, 0};
    *(bf16x8*)&p[off] = z;
}

// ---------------- deconv upsample (stride 2, pad 1, k=4) ----------------
// NOTE: must run AFTER k_corr — k_corr's packed epilogue writes each pixel's
// full 256-B block (channel 49 slots zeroed); this kernel then fills conf
// into channel 49.
__global__ void k_upsample(const float* __restrict__ flow, const float* __restrict__ conf,
                           const float* __restrict__ up_flow_w, const float* __restrict__ up_conf_w,
                           float* __restrict__ flow_up, unsigned short* __restrict__ xin) {
    int idx = blockIdx.x * 256 + threadIdx.x;
    if (idx >= B * 3 * HW) return;
    int x = idx % W;
    int y = (idx / W) % H;
    int ch = (idx / HW) % 3;
    int b = idx / (3 * HW);
    const float* in;
    const float* w;
    if (ch < 2) { in = flow + (size_t)(b * 2 + ch) * 6400; w = up_flow_w + ch * 16; }
    else        { in = conf + (size_t)b * 6400;            w = up_conf_w; }
    float acc = 0.f;
#pragma unroll
    for (int dy = 0; dy < 4; ++dy) {
        int tny = y + 1 - dy;
        if (tny < 0 || (tny & 1)) continue;
        int iy = tny >> 1;
        if (iy >= 80) continue;
#pragma unroll
        for (int dx = 0; dx < 4; ++dx) {
            int tnx = x + 1 - dx;
            if (tnx < 0 || (tnx & 1)) continue;
            int ix = tnx >> 1;
            if (ix >= 80) continue;
            acc += in[iy * 80 + ix] * w[dy * 4 + dx];
        }
    }
    if (ch < 2) flow_up[(size_t)(b * 2 + ch) * HW + y * W + x] = acc;
    else {
        // conf is channel 49: chunk 1, within 17
        size_t off = ((size_t)(b * WP + y + 1) * WP + (x + 1)) * 128 + 64 + 17;
        unsigned short h = f2bf(acc);
        xin[off] = h;
        xin[off + 32] = f2bf(acc - bf2f(h));
    }
}

// ---------------- dilated self-correlation (PATCH=7, DIL=2) ----------------
// 4-channel f32x4 staging (ds_read_b128 taps) + packed 16B epilogue stores.
// Channel 49 slots written ZERO here (conf lands there later via k_upsample).
__global__ __launch_bounds__(256, 4) void k_corr(const float* __restrict__ feats,
                                                 unsigned short* __restrict__ xin) {
    const int bid = blockIdx.x;
    const int b = bid & 7;
    const int t = bid >> 3;           // 0..99
    const int x0 = (t % 5) * 32;
    const int y0 = (t / 5) * 8;
    const int tid = threadIdx.x;
    const int tx = tid & 31;
    const int ty = tid >> 5;          // 0..7
    __shared__ f32x4 sh[2][880];      // 20 rows x 44 cols x 4 ch, double-buffered (28.2 KB)
    float acc[49];
#pragma unroll
    for (int i = 0; i < 49; ++i) acc[i] = 0.f;

    int soff[4]; bool sval[4];
#pragma unroll
    for (int s = 0; s < 4; ++s) {
        int i = tid + s * 256;
        int r = i / 44, cc = i % 44;
        int gy = y0 + r - 6, gx = x0 + cc - 6;
        sval[s] = (i < 880) && gy >= 0 && gy < H && gx >= 0 && gx < W;
        soff[s] = sval[s] ? (gy * W + gx) : 0;
    }
    const float* f = feats + (size_t)b * 2 * C * HW;  // feats[b, 0]
    f32x4 pre[4];
#pragma unroll
    for (int s = 0; s < 4; ++s)
#pragma unroll
        for (int c4 = 0; c4 < 4; ++c4)
            pre[s][c4] = sval[s] ? f[(size_t)c4 * HW + soff[s]] : 0.f;

    for (int cg = 0; cg < 32; ++cg) {          // channel groups of 4
        f32x4* buf = sh[cg & 1];
#pragma unroll
        for (int s = 0; s < 4; ++s) {
            int i = tid + s * 256;
            if (i < 880) buf[i] = pre[s];
        }
        if (cg < 31) {
            const float* fn = f + (size_t)(cg + 1) * 4 * HW;
#pragma unroll
            for (int s = 0; s < 4; ++s)
#pragma unroll
                for (int c4 = 0; c4 < 4; ++c4)
                    pre[s][c4] = sval[s] ? fn[(size_t)c4 * HW + soff[s]] : 0.f;
        }
        __syncthreads();
        f32x4 ctr = buf[(ty + 6) * 44 + tx + 6];
#pragma unroll
        for (int dy = 0; dy < 7; ++dy) {
            const f32x4* row = &buf[(ty + 2 * dy) * 44 + tx];
#pragma unroll
            for (int dx = 0; dx < 7; ++dx) {
                f32x4 rv = row[2 * dx];
                float a = acc[dy * 7 + dx];
                a += ctr[0] * rv[0];   // strictly channel-sequential
                a += ctr[1] * rv[1];
                a += ctr[2] * rv[2];
                a += ctr[3] * rv[3];
                acc[dy * 7 + dx] = a;
            }
        }
        __syncthreads();
    }
    // epilogue: pack the pixel's 256-B block (hi|lo chunk-pair layout) and
    // store as 16 x dwordx4. Short j of 128: chunk=j>>6, plane=(j>>5)&1,
    // ch = chunk*32 + (j&31); ch>=49 -> 0 (49=conf, filled by k_upsample after).
    size_t pbase = ((size_t)(b * WP + y0 + ty + 1) * WP + (x0 + tx + 1)) * 128;
#pragma unroll
    for (int g = 0; g < 16; ++g) {
        bf16x8 pk;
#pragma unroll
        for (int e = 0; e < 8; ++e) {
            const int ch = ((g >> 3) * 32) + ((g & 3) * 8) + e;
            const int plane = (g >> 2) & 1;
            unsigned short os = 0;
            if (ch < 49) {
                float v = acc[ch];
                v = (v > 0.f) ? v : 0.1f * v;   // leaky_relu(0.1)
                v *= 0.0078125f;                // / 128
                unsigned short h = f2bf(v);
                os = plane ? f2bf(v - bf2f(h)) : h;
            }
            pk[e] = (short)os;
        }
        *(bf16x8*)&xin[pbase + g * 8] = pk;
    }
}

// ---------------- split-bf16 MFMA 3x3 conv + bias + leaky_relu ----------------
// R7: A+W BOTH in LDS (the two measured-fast operand paths of R3), but the
// tile is split in x so TWO blocks genuinely fit per CU:
//   A-tile = 4 padded rows x 82 cols (80 interior + real pad cols) x 128 B
//          = 41,984 B;  W (COB=32) = 36,864 B;  total 78,848 B -> 2 blocks/CU
//   with ~6 KB slack (R6's exact-160KiB fit only reached ~1.6 blocks/CU).
// 4 waves = (row rw) x (co-half ch): each wave 5 mt-tiles x 16 cos.
// One block's stage+vmcnt(0) drain overlaps the co-resident block's MFMAs;
// 2 waves/SIMD halve the serial-issue exposure that capped R3.
// Same A XOR-swizzle, same W rotate-swizzle, same MFMA order -> bit-identical.
template<int CIN, int COUT, int NCO, int OUTF>
__global__ __launch_bounds__(256, 2) void k_convM(
    const unsigned short* __restrict__ in,
    const unsigned short* __restrict__ w_hi,  const unsigned short* __restrict__ w_lo,
    const float* __restrict__ bias,
    unsigned short* __restrict__ out_pk, float* __restrict__ out_f) {
    constexpr int COB = 32;
    constexpr int NKC = CIN / 32;
    constexpr int CI2 = 2 * CIN;
    constexpr int WSZ = 9 * COB * 32;        // 9216 shorts per weight plane
    constexpr int GPP = 9 * COB * 4;         // 1152 granules per plane
    __shared__ __align__(128) unsigned short At[4 * 82 * 64];  // 41,984 B
    __shared__ __align__(128) unsigned short wl[2 * WSZ];      // 36,864 B

    const int bid = blockIdx.x;
    const int b = bid & 7;
    const int t = bid >> 3;
    const int co0 = (t % NCO) * COB;
    const int xh  = (t / NCO) & 1;           // x half: 0 or 1
    const int ybx = t / (NCO * 2);           // 0..79
    const int wave = threadIdx.x >> 6;
    const int lane = threadIdx.x & 63;
    const int rw = wave & 1;                 // output row within pair
    const int ch = wave >> 1;                // co half (16 cos)
    const int y = ybx * 2 + rw;              // interior row 0..159
    const int x0g = xh * 80;                 // interior x base
    const int m = lane & 15, q = lane >> 4;
    const int arow0 = b * WP + 2 * ybx;      // padded row base of the A-tile
    const int coL = ch * 16 + m;             // local co in [0,32)

    f32x4 acc[5];
#pragma unroll
    for (int mt = 0; mt < 5; ++mt) acc[mt] = (f32x4){0.f, 0.f, 0.f, 0.f};

    bf16x8 ah[2][5], al[2][5], bh[2], bl[2];

    // A-frag loader: tile col = (m + mt*16) + dx in [0,81] (pad cols are real)
    auto lda = [&](int dy, int dx, bf16x8* dsth, bf16x8* dstl) {
        const int cb = m + dx;
#pragma unroll
        for (int mt = 0; mt < 5; ++mt) {
            const int pl = (rw + dy) * 82 + cb + mt * 16;
            const int g16 = (pl << 3) ^ (pl & 7) ^ q;
            dsth[mt] = *(const bf16x8*)&At[g16 * 8];
            dstl[mt] = *(const bf16x8*)&At[(g16 ^ 4) * 8];
        }
    };
    auto ldw = [&](int tap, bf16x8& h, bf16x8& l) {
        const int slot = (q + (coL >> 1)) & 3;
        const int woff = (tap * COB + coL) * 32 + slot * 8;
        h = *(const bf16x8*)&wl[woff];
        l = *(const bf16x8*)&wl[WSZ + woff];
    };

    for (int kc = 0; kc < NKC; ++kc) {
        __syncthreads();   // all waves done reading prev kc's LDS

        // ---- stage A-tile: 41 chunks of 1 KB (4 rows x 82 cols x 8 granules) ----
#pragma unroll
        for (int k = 0; k < 11; ++k) {
            int c = k * 4 + wave;
            if (c < 41) {
                int ga = c * 64 + lane;          // 16-B granule id
                int pl = ga >> 3;                // tile pixel (r*82 + cx)
                int r  = pl / 82;
                int cx = pl - r * 82;
                int slot = (ga & 7) ^ (pl & 7);  // inverse XOR swizzle on SOURCE
                const unsigned short* src =
                    in + ((size_t)(arow0 + r) * WP + x0g + cx) * CI2 + kc * 64 + slot * 8;
                gload16(src, At + c * 512);
            }
        }
        // ---- stage W: hi plane then lo plane, 36 chunks ----
#pragma unroll
        for (int k = 0; k < 9; ++k) {
            int c = k * 4 + wave;
            int gw = c * 64 + lane;
            int p  = (c * 64) >= GPP;            // chunk-uniform plane select
            int idx = gw - p * GPP;
            int cc = idx >> 2, sl = idx & 3;
            int tap = cc / COB, co = cc % COB;
            int g = (sl - (co >> 1)) & 3;        // inverse of rotate swizzle
            const unsigned short* wsrc =
                (p ? w_lo : w_hi) + (tap * COUT + co0 + co) * CIN + kc * 32 + g * 8;
            gload16(wsrc, wl + c * 512);
        }
        asm volatile("s_waitcnt vmcnt(0)" ::: "memory");
        __syncthreads();   // LDS tile + weights visible to all waves

        lda(0, 0, ah[0], al[0]);   // tap 0 prefetch
        ldw(0, bh[0], bl[0]);

#pragma unroll
        for (int tap = 0; tap < 9; ++tap) {
            const int cur = tap & 1, nxt = cur ^ 1;
            if (tap < 8) {   // prefetch tap+1 into the other reg buffer
                const int tap1 = tap + 1;
                lda(tap1 / 3, tap1 % 3, ah[nxt], al[nxt]);
                ldw(tap1, bh[nxt], bl[nxt]);
            }
#pragma unroll
            for (int mt = 0; mt < 5; ++mt) {
                acc[mt] = __builtin_amdgcn_mfma_f32_16x16x32_bf16(ah[cur][mt], bh[cur], acc[mt], 0, 0, 0);
                acc[mt] = __builtin_amdgcn_mfma_f32_16x16x32_bf16(ah[cur][mt], bl[cur], acc[mt], 0, 0, 0);
                acc[mt] = __builtin_amdgcn_mfma_f32_16x16x32_bf16(al[cur][mt], bh[cur], acc[mt], 0, 0, 0);
            }
        }
    }
    // epilogue: D col = lane&15 = co, D row = q*4+r = pixel within m-tile
    {
        const int co = co0 + coL;
        const float bv = bias[co];
#pragma unroll
        for (int mt = 0; mt < 5; ++mt) {
#pragma unroll
            for (int r = 0; r < 4; ++r) {
                float v = acc[mt][r] + bv;
                v = (v > 0.f) ? v : 0.1f * v;
                const int x = x0g + mt * 16 + q * 4 + r;
                if (OUTF) {
                    out_f[((size_t)(b * COUT + co)) * HW + y * W + x] = v;
                } else {
                    const size_t off = ((size_t)(b * WP + y + 1) * WP + (x + 1)) * (2 * COUT)
                                     + ((co >> 5) * 64) + (co & 31);
                    unsigned short h = f2bf(v);
                    out_pk[off] = h;
                    out_pk[off + 32] = f2bf(v - bf2f(h));
                }
            }
        }
    }
}

// ---------------- fused heads (5x5 convs) + warp + sigmoid ----------------
__global__ __launch_bounds__(256) void k_head(const float* __restrict__ x3,
                                              const float* __restrict__ wHT,
                                              const float* __restrict__ disp_b,
                                              const float* __restrict__ conf_b,
                                              const float* __restrict__ flow_up,
                                              float* __restrict__ out) {
    const int bid = blockIdx.x;
    const int b = bid & 7;
    const int t = bid >> 3;           // 0..99
    const int x0 = (t % 10) * 16, y0 = (t / 10) * 16;
    const int tx = threadIdx.x & 15, ty = threadIdx.x >> 4;
    const int tid = threadIdx.x;
    __shared__ float sh[2 * 400];  // 2 channels x 20x20
    float a0 = 0.f, a1 = 0.f, a2 = 0.f;
    const float* xb = x3 + (size_t)(b * 32) * HW;
    for (int ci = 0; ci < 32; ci += 2) {
        __syncthreads();
        for (int i = tid; i < 800; i += 256) {
            int cc = i / 400;
            int rem = i - cc * 400;
            int r = rem / 20, c2 = rem % 20;
            int gy = y0 + r - 2, gx = x0 + c2 - 2;
            float v = 0.f;
            if (gy >= 0 && gy < H && gx >= 0 && gx < W)
                v = xb[(size_t)(ci + cc) * HW + gy * W + gx];
            sh[i] = v;
        }
        __syncthreads();
#pragma unroll
        for (int cc = 0; cc < 2; ++cc) {
            const float* t2 = sh + cc * 400;
            const float* wp = wHT + (size_t)(ci + cc) * 75;
#pragma unroll
            for (int k = 0; k < 25; ++k) {
                float v = t2[(ty + k / 5) * 20 + tx + (k % 5)];
                a0 += v * wp[k * 3 + 0];
                a1 += v * wp[k * 3 + 1];
                a2 += v * wp[k * 3 + 2];
            }
        }
    }
    const int gx = x0 + tx, gy = y0 + ty;
    float d0 = a0 + disp_b[0];
    float d1 = a1 + disp_b[1];
    float cf = a2 + conf_b[0];
    cf = 1.f / (1.f + expf(-cf));

    float px = (float)gx + d0, py = (float)gy + d1;
    float x0f = floorf(px), y0f = floorf(py);
    float wx1 = px - x0f, wx0 = 1.f - wx1;
    float wy1 = py - y0f, wy0 = 1.f - wy1;
    const float* f0 = flow_up + (size_t)(b * 2) * HW;
    const float* f1 = f0 + HW;

    float m00, m01, m10, m11;
    float a00, a01, a10, a11;
    float b00, b01, b10, b11;
    auto corner = [&](float xf, float yf, float& m, float& c0, float& c1) {
        bool valid = (xf >= 0.f) && (xf <= (float)(W - 1)) && (yf >= 0.f) && (yf <= (float)(H - 1));
        m = valid ? 1.f : 0.f;
        if (valid) {
            int xi = (int)xf, yi = (int)yf;
            int o = yi * W + xi;
            c0 = f0[o]; c1 = f1[o];
        } else { c0 = 0.f; c1 = 0.f; }
    };
    corner(x0f,       y0f,       m00, a00, b00);
    corner(x0f + 1.f, y0f,       m01, a01, b01);
    corner(x0f,       y0f + 1.f, m10, a10, b10);
    corner(x0f + 1.f, y0f + 1.f, m11, a11, b11);

    float o0 = wy0 * (wx0 * a00 + wx1 * a01) + wy1 * (wx0 * a10 + wx1 * a11);
    float o1 = wy0 * (wx0 * b00 + wx1 * b01) + wy1 * (wx0 * b10 + wx1 * b11);
    float msk = wy0 * (wx0 * m00 + wx1 * m01) + wy1 * (wx0 * m10 + wx1 * m11);
    float mask = (msk >= 1.f) ? 1.f : 0.f;

    int o = gy * W + gx;
    out[(size_t)(b * 2 + 0) * HW + o] = o0 * mask;
    out[(size_t)(b * 2 + 1) * HW + o] = o1 * mask;
    out[(size_t)B * 2 * HW + (size_t)b * HW + o] = cf;
}

extern "C" void kernel_launch(void* const* d_in, const int* in_sizes, int n_in,
                              void* d_out, int out_size, void* d_ws, size_t ws_size,
                              hipStream_t stream) {
    const float* feats     = (const float*)d_in[0];
    const float* flow      = (const float*)d_in[1];
    const float* conf      = (const float*)d_in[2];
    const float* up_conf_w = (const float*)d_in[3];
    const float* up_flow_w = (const float*)d_in[4];
    const float* w1        = (const float*)d_in[5];
    const float* b1        = (const float*)d_in[6];
    const float* w2        = (const float*)d_in[7];
    const float* b2        = (const float*)d_in[8];
    const float* w3        = (const float*)d_in[9];
    const float* b3        = (const float*)d_in[10];
    const float* disp_w    = (const float*)d_in[11];
    const float* disp_b    = (const float*)d_in[12];
    const float* conf_w    = (const float*)d_in[13];
    const float* conf_b    = (const float*)d_in[14];
    float* out = (float*)d_out;

    // workspace layout (bytes)
    char* p = (char*)d_ws;
    const size_t SZ_XIN = (size_t)B * WP * WP * 128 * 2;   // 53,747,712 (hi|lo interleaved)
    const size_t SZ_X1  = (size_t)B * WP * WP * 256 * 2;   // 107,495,424
    unsigned short* xin = (unsigned short*)p;
    unsigned short* x1  = (unsigned short*)(p + SZ_XIN);
    char* p2 = p + SZ_XIN + SZ_X1;
    float* flow_up = (float*)p2;                 // 1,638,400 B
    float* wHT     = (float*)(p2 + 1638400);     // 9,600 B
    unsigned short* wpk1h = (unsigned short*)(p2 + 1648000);
    unsigned short* wpk1l = wpk1h + 73728;
    unsigned short* wpk2h = wpk1l + 73728;
    unsigned short* wpk2l = wpk2h + 73728;
    unsigned short* wpk3h = wpk2l + 73728;
    unsigned short* wpk3l = wpk3h + 18432;
    // aliases: x2 reuses xin (same geometry 2C=128, ring stays zero); x3 reuses x1
    unsigned short* x2 = xin;
    float* x3 = (float*)x1;   // 26.2 MB <= SZ_X1, x1 dead after conv2

    k_repack<<<658, 256, 0, stream>>>(w1, w2, w3, disp_w, conf_w,
                                      wpk1h, wpk1l, wpk2h, wpk2l, wpk3h, wpk3l, wHT);
    k_zeropad<<<966, 256, 0, stream>>>(xin, x1);
    // ORDER: k_corr writes each pixel's full 256-B block (ch 49 zeroed);
    // k_upsample then fills conf into ch 49. Same stream -> sequential.
    k_corr<<<800, 256, 0, stream>>>(feats, xin);
    k_upsample<<<(B * 3 * HW + 255) / 256, 256, 0, stream>>>(flow, conf, up_flow_w, up_conf_w,
                                                             flow_up, xin);
    // grids: img(8) x NCO x xh(2) x ybx(80)
    k_convM<64, 128, 4, 0><<<5120, 256, 0, stream>>>(xin, wpk1h, wpk1l, b1, x1, nullptr);
    k_convM<128, 64, 2, 0><<<2560, 256, 0, stream>>>(x1, wpk2h, wpk2l, b2, x2, nullptr);
    k_convM<64, 32, 1, 1><<<1280, 256, 0, stream>>>(x2, wpk3h, wpk3l, b3, nullptr, x3);
    k_head<<<800, 256, 0, stream>>>(x3, wHT, disp_b, conf_b, flow_up, out);
}

// Round 8
// 611.604 us; speedup vs baseline: 1.3208x; 1.1099x over previous
//
#include <hip/hip_runtime.h>
#include <math.h>

#define B 8
#define C 128
#define H 160
#define W 160
#define HW 25600
#define WP 162   // padded width/height (pad=1 ring of zeros)

typedef short bf16x8 __attribute__((ext_vector_type(8)));
typedef float f32x4  __attribute__((ext_vector_type(4)));

__device__ __forceinline__ unsigned short f2bf(float x) {  // RNE
    union { float f; unsigned u; } v; v.f = x;
    unsigned r = v.u + 0x7fff + ((v.u >> 16) & 1);
    return (unsigned short)(r >> 16);
}
__device__ __forceinline__ float bf2f(unsigned short h) {
    union { unsigned u; float f; } v; v.u = ((unsigned)h) << 16;
    return v.f;
}

// async global->LDS, 16 B per lane; LDS dest = uniform base + lane*16
__device__ __forceinline__ void gload16(const unsigned short* g, unsigned short* l) {
    __builtin_amdgcn_global_load_lds(
        (const __attribute__((address_space(1))) void*)g,
        (__attribute__((address_space(3))) void*)l, 16, 0, 0);
}

// Activation layout ("chunk-pair interleaved", per padded pixel):
//   addr(px, ch, plane) = px*(2*C) + (ch>>5)*64 + plane*32 + (ch&31)

// ---------------- weight repack: split-bf16 [tap][co][ci] (R3 layout) ----------------
__global__ void k_repack(const float* __restrict__ w1, const float* __restrict__ w2,
                         const float* __restrict__ w3, const float* __restrict__ dw,
                         const float* __restrict__ cw,
                         unsigned short* __restrict__ wpk1h, unsigned short* __restrict__ wpk1l,
                         unsigned short* __restrict__ wpk2h, unsigned short* __restrict__ wpk2l,
                         unsigned short* __restrict__ wpk3h, unsigned short* __restrict__ wpk3l,
                         float* __restrict__ wHT) {
    int idx = blockIdx.x * 256 + threadIdx.x;
    if (idx < 73728) {  // w1: [t][co=128][ci=64]  (ci 0..49 real, 50..63 zero)
        int t = idx / 8192; int r = idx % 8192; int co = r / 64; int ci = r % 64;
        float v = (ci < 50) ? w1[(co * 50 + ci) * 9 + t] : 0.f;
        unsigned short h = f2bf(v);
        wpk1h[idx] = h; wpk1l[idx] = f2bf(v - bf2f(h));
        return;
    }
    idx -= 73728;
    if (idx < 73728) {  // w2: [t][co=64][ci=128]
        int t = idx / 8192; int r = idx % 8192; int co = r / 128; int ci = r % 128;
        float v = w2[(co * 128 + ci) * 9 + t];
        unsigned short h = f2bf(v);
        wpk2h[idx] = h; wpk2l[idx] = f2bf(v - bf2f(h));
        return;
    }
    idx -= 73728;
    if (idx < 18432) {  // w3: [t][co=32][ci=64]
        int t = idx / 2048; int r = idx % 2048; int co = r / 64; int ci = r % 64;
        float v = w3[(co * 64 + ci) * 9 + t];
        unsigned short h = f2bf(v);
        wpk3h[idx] = h; wpk3l[idx] = f2bf(v - bf2f(h));
        return;
    }
    idx -= 18432;
    if (idx < 2400) {   // heads (fp32): wHT[ci][k][3]: 0,1=disp 2=conf
        int ci = idx / 75; int rem = idx % 75; int k = rem / 3; int co = rem % 3;
        wHT[idx] = (co < 2) ? dw[(co * 32 + ci) * 25 + k] : cw[ci * 25 + k];
    }
}

// ---------------- zero the pad rings of xin (2C=128) and x1 (2C=256) ----------------
__global__ void k_zeropad(unsigned short* __restrict__ xin, unsigned short* __restrict__ x1) {
    int idx = blockIdx.x * 256 + threadIdx.x;
    unsigned short* p; int C2;
    if (idx < 82432) { p = xin; C2 = 128; }
    else {
        idx -= 82432;
        if (idx >= 164864) return;
        p = x1; C2 = 256;
    }
    int chunks = C2 / 8;
    int percnt = 644 * chunks;
    int img = idx / percnt;
    int r = idx % percnt;
    int rp = r / chunks; int ch = r % chunks;
    int yy, xx;
    if (rp < 162)      { yy = 0;   xx = rp; }
    else if (rp < 324) { yy = 161; xx = rp - 162; }
    else { int s = rp - 324; yy = 1 + (s >> 1); xx = (s & 1) ? 161 : 0; }
    size_t off = ((size_t)(img * WP + yy) * WP + xx) * C2 + ch * 8;
    bf16x8 z = {0, 0, 0, 0, 0, 0, 0, 0};
    *(bf16x8*)&p[off] = z;
}

// ---------------- deconv upsample (stride 2, pad 1, k=4) ----------------
// NOTE: must run AFTER k_corr — k_corr's packed epilogue writes each pixel's
// full 256-B block (channel 49 slots zeroed); this kernel then fills conf
// into channel 49.
__global__ void k_upsample(const float* __restrict__ flow, const float* __restrict__ conf,
                           const float* __restrict__ up_flow_w, const float* __restrict__ up_conf_w,
                           float* __restrict__ flow_up, unsigned short* __restrict__ xin) {
    int idx = blockIdx.x * 256 + threadIdx.x;
    if (idx >= B * 3 * HW) return;
    int x = idx % W;
    int y = (idx / W) % H;
    int ch = (idx / HW) % 3;
    int b = idx / (3 * HW);
    const float* in;
    const float* w;
    if (ch < 2) { in = flow + (size_t)(b * 2 + ch) * 6400; w = up_flow_w + ch * 16; }
    else        { in = conf + (size_t)b * 6400;            w = up_conf_w; }
    float acc = 0.f;
#pragma unroll
    for (int dy = 0; dy < 4; ++dy) {
        int tny = y + 1 - dy;
        if (tny < 0 || (tny & 1)) continue;
        int iy = tny >> 1;
        if (iy >= 80) continue;
#pragma unroll
        for (int dx = 0; dx < 4; ++dx) {
            int tnx = x + 1 - dx;
            if (tnx < 0 || (tnx & 1)) continue;
            int ix = tnx >> 1;
            if (ix >= 80) continue;
            acc += in[iy * 80 + ix] * w[dy * 4 + dx];
        }
    }
    if (ch < 2) flow_up[(size_t)(b * 2 + ch) * HW + y * W + x] = acc;
    else {
        // conf is channel 49: chunk 1, within 17
        size_t off = ((size_t)(b * WP + y + 1) * WP + (x + 1)) * 128 + 64 + 17;
        unsigned short h = f2bf(acc);
        xin[off] = h;
        xin[off + 32] = f2bf(acc - bf2f(h));
    }
}

// ---------------- dilated self-correlation (PATCH=7, DIL=2) ----------------
// R8: restore the R5 single-barrier loop (R6 accidentally added a trailing
// __syncthreads per channel-group: +32 barriers/block -> +~30 us). The single
// barrier is race-free with the double buffer: iter k+2's writes to buf[k&1]
// happen after iter k+1's barrier, which no wave passes before finishing
// iter k's reads. 4-channel f32x4 staging + packed 16B epilogue stores.
// Channel 49 slots written ZERO here (conf lands there later via k_upsample).
__global__ __launch_bounds__(256, 4) void k_corr(const float* __restrict__ feats,
                                                 unsigned short* __restrict__ xin) {
    const int bid = blockIdx.x;
    const int b = bid & 7;
    const int t = bid >> 3;           // 0..99
    const int x0 = (t % 5) * 32;
    const int y0 = (t / 5) * 8;
    const int tid = threadIdx.x;
    const int tx = tid & 31;
    const int ty = tid >> 5;          // 0..7
    __shared__ f32x4 sh[2][880];      // 20 rows x 44 cols x 4 ch, double-buffered (28.2 KB)
    float acc[49];
#pragma unroll
    for (int i = 0; i < 49; ++i) acc[i] = 0.f;

    int soff[4]; bool sval[4];
#pragma unroll
    for (int s = 0; s < 4; ++s) {
        int i = tid + s * 256;
        int r = i / 44, cc = i % 44;
        int gy = y0 + r - 6, gx = x0 + cc - 6;
        sval[s] = (i < 880) && gy >= 0 && gy < H && gx >= 0 && gx < W;
        soff[s] = sval[s] ? (gy * W + gx) : 0;
    }
    const float* f = feats + (size_t)b * 2 * C * HW;  // feats[b, 0]
    f32x4 pre[4];
#pragma unroll
    for (int s = 0; s < 4; ++s)
#pragma unroll
        for (int c4 = 0; c4 < 4; ++c4)
            pre[s][c4] = sval[s] ? f[(size_t)c4 * HW + soff[s]] : 0.f;

    for (int cg = 0; cg < 32; ++cg) {          // channel groups of 4
        f32x4* buf = sh[cg & 1];
#pragma unroll
        for (int s = 0; s < 4; ++s) {
            int i = tid + s * 256;
            if (i < 880) buf[i] = pre[s];
        }
        if (cg < 31) {
            const float* fn = f + (size_t)(cg + 1) * 4 * HW;
#pragma unroll
            for (int s = 0; s < 4; ++s)
#pragma unroll
                for (int c4 = 0; c4 < 4; ++c4)
                    pre[s][c4] = sval[s] ? fn[(size_t)c4 * HW + soff[s]] : 0.f;
        }
        __syncthreads();
        f32x4 ctr = buf[(ty + 6) * 44 + tx + 6];
#pragma unroll
        for (int dy = 0; dy < 7; ++dy) {
            const f32x4* row = &buf[(ty + 2 * dy) * 44 + tx];
#pragma unroll
            for (int dx = 0; dx < 7; ++dx) {
                f32x4 rv = row[2 * dx];
                float a = acc[dy * 7 + dx];
                a += ctr[0] * rv[0];   // strictly channel-sequential
                a += ctr[1] * rv[1];
                a += ctr[2] * rv[2];
                a += ctr[3] * rv[3];
                acc[dy * 7 + dx] = a;
            }
        }
    }
    // epilogue: pack the pixel's 256-B block (hi|lo chunk-pair layout) and
    // store as 16 x dwordx4. Short j of 128: chunk=j>>6, plane=(j>>5)&1,
    // ch = chunk*32 + (j&31); ch>=49 -> 0 (49=conf, filled by k_upsample after).
    size_t pbase = ((size_t)(b * WP + y0 + ty + 1) * WP + (x0 + tx + 1)) * 128;
#pragma unroll
    for (int g = 0; g < 16; ++g) {
        bf16x8 pk;
#pragma unroll
        for (int e = 0; e < 8; ++e) {
            const int ch = ((g >> 3) * 32) + ((g & 3) * 8) + e;
            const int plane = (g >> 2) & 1;
            unsigned short os = 0;
            if (ch < 49) {
                float v = acc[ch];
                v = (v > 0.f) ? v : 0.1f * v;   // leaky_relu(0.1)
                v *= 0.0078125f;                // / 128
                unsigned short h = f2bf(v);
                os = plane ? f2bf(v - bf2f(h)) : h;
            }
            pk[e] = (short)os;
        }
        *(bf16x8*)&xin[pbase + g * 8] = pk;
    }
}

// ---------------- split-bf16 MFMA 3x3 conv + bias + leaky_relu ----------------
// R7: A+W BOTH in LDS; tile split in x so TWO blocks fit per CU:
//   A-tile = 4 padded rows x 82 cols x 128 B = 41,984 B; W (COB=32) = 36,864 B;
//   total 78,848 B -> 2 blocks/CU with ~6 KB slack.
// 4 waves = (row rw) x (co-half ch): each wave 5 mt-tiles x 16 cos.
// Same A XOR-swizzle, same W rotate-swizzle, same MFMA order -> bit-identical.
template<int CIN, int COUT, int NCO, int OUTF>
__global__ __launch_bounds__(256, 2) void k_convM(
    const unsigned short* __restrict__ in,
    const unsigned short* __restrict__ w_hi,  const unsigned short* __restrict__ w_lo,
    const float* __restrict__ bias,
    unsigned short* __restrict__ out_pk, float* __restrict__ out_f) {
    constexpr int COB = 32;
    constexpr int NKC = CIN / 32;
    constexpr int CI2 = 2 * CIN;
    constexpr int WSZ = 9 * COB * 32;        // 9216 shorts per weight plane
    constexpr int GPP = 9 * COB * 4;         // 1152 granules per plane
    __shared__ __align__(128) unsigned short At[4 * 82 * 64];  // 41,984 B
    __shared__ __align__(128) unsigned short wl[2 * WSZ];      // 36,864 B

    const int bid = blockIdx.x;
    const int b = bid & 7;
    const int t = bid >> 3;
    const int co0 = (t % NCO) * COB;
    const int xh  = (t / NCO) & 1;           // x half: 0 or 1
    const int ybx = t / (NCO * 2);           // 0..79
    const int wave = threadIdx.x >> 6;
    const int lane = threadIdx.x & 63;
    const int rw = wave & 1;                 // output row within pair
    const int ch = wave >> 1;                // co half (16 cos)
    const int y = ybx * 2 + rw;              // interior row 0..159
    const int x0g = xh * 80;                 // interior x base
    const int m = lane & 15, q = lane >> 4;
    const int arow0 = b * WP + 2 * ybx;      // padded row base of the A-tile
    const int coL = ch * 16 + m;             // local co in [0,32)

    f32x4 acc[5];
#pragma unroll
    for (int mt = 0; mt < 5; ++mt) acc[mt] = (f32x4){0.f, 0.f, 0.f, 0.f};

    bf16x8 ah[2][5], al[2][5], bh[2], bl[2];

    // A-frag loader: tile col = (m + mt*16) + dx in [0,81] (pad cols are real)
    auto lda = [&](int dy, int dx, bf16x8* dsth, bf16x8* dstl) {
        const int cb = m + dx;
#pragma unroll
        for (int mt = 0; mt < 5; ++mt) {
            const int pl = (rw + dy) * 82 + cb + mt * 16;
            const int g16 = (pl << 3) ^ (pl & 7) ^ q;
            dsth[mt] = *(const bf16x8*)&At[g16 * 8];
            dstl[mt] = *(const bf16x8*)&At[(g16 ^ 4) * 8];
        }
    };
    auto ldw = [&](int tap, bf16x8& h, bf16x8& l) {
        const int slot = (q + (coL >> 1)) & 3;
        const int woff = (tap * COB + coL) * 32 + slot * 8;
        h = *(const bf16x8*)&wl[woff];
        l = *(const bf16x8*)&wl[WSZ + woff];
    };

    for (int kc = 0; kc < NKC; ++kc) {
        __syncthreads();   // all waves done reading prev kc's LDS

        // ---- stage A-tile: 41 chunks of 1 KB (4 rows x 82 cols x 8 granules) ----
#pragma unroll
        for (int k = 0; k < 11; ++k) {
            int c = k * 4 + wave;
            if (c < 41) {
                int ga = c * 64 + lane;          // 16-B granule id
                int pl = ga >> 3;                // tile pixel (r*82 + cx)
                int r  = pl / 82;
                int cx = pl - r * 82;
                int slot = (ga & 7) ^ (pl & 7);  // inverse XOR swizzle on SOURCE
                const unsigned short* src =
                    in + ((size_t)(arow0 + r) * WP + x0g + cx) * CI2 + kc * 64 + slot * 8;
                gload16(src, At + c * 512);
            }
        }
        // ---- stage W: hi plane then lo plane, 36 chunks ----
#pragma unroll
        for (int k = 0; k < 9; ++k) {
            int c = k * 4 + wave;
            int gw = c * 64 + lane;
            int p  = (c * 64) >= GPP;            // chunk-uniform plane select
            int idx = gw - p * GPP;
            int cc = idx >> 2, sl = idx & 3;
            int tap = cc / COB, co = cc % COB;
            int g = (sl - (co >> 1)) & 3;        // inverse of rotate swizzle
            const unsigned short* wsrc =
                (p ? w_lo : w_hi) + (tap * COUT + co0 + co) * CIN + kc * 32 + g * 8;
            gload16(wsrc, wl + c * 512);
        }
        asm volatile("s_waitcnt vmcnt(0)" ::: "memory");
        __syncthreads();   // LDS tile + weights visible to all waves

        lda(0, 0, ah[0], al[0]);   // tap 0 prefetch
        ldw(0, bh[0], bl[0]);

#pragma unroll
        for (int tap = 0; tap < 9; ++tap) {
            const int cur = tap & 1, nxt = cur ^ 1;
            if (tap < 8) {   // prefetch tap+1 into the other reg buffer
                const int tap1 = tap + 1;
                lda(tap1 / 3, tap1 % 3, ah[nxt], al[nxt]);
                ldw(tap1, bh[nxt], bl[nxt]);
            }
#pragma unroll
            for (int mt = 0; mt < 5; ++mt) {
                acc[mt] = __builtin_amdgcn_mfma_f32_16x16x32_bf16(ah[cur][mt], bh[cur], acc[mt], 0, 0, 0);
                acc[mt] = __builtin_amdgcn_mfma_f32_16x16x32_bf16(ah[cur][mt], bl[cur], acc[mt], 0, 0, 0);
                acc[mt] = __builtin_amdgcn_mfma_f32_16x16x32_bf16(al[cur][mt], bh[cur], acc[mt], 0, 0, 0);
            }
        }
    }
    // epilogue: D col = lane&15 = co, D row = q*4+r = pixel within m-tile
    {
        const int co = co0 + coL;
        const float bv = bias[co];
#pragma unroll
        for (int mt = 0; mt < 5; ++mt) {
#pragma unroll
            for (int r = 0; r < 4; ++r) {
                float v = acc[mt][r] + bv;
                v = (v > 0.f) ? v : 0.1f * v;
                const int x = x0g + mt * 16 + q * 4 + r;
                if (OUTF) {
                    out_f[((size_t)(b * COUT + co)) * HW + y * W + x] = v;
                } else {
                    const size_t off = ((size_t)(b * WP + y + 1) * WP + (x + 1)) * (2 * COUT)
                                     + ((co >> 5) * 64) + (co & 31);
                    unsigned short h = f2bf(v);
                    out_pk[off] = h;
                    out_pk[off + 32] = f2bf(v - bf2f(h));
                }
            }
        }
    }
}

// ---------------- fused heads (5x5 convs) + warp + sigmoid ----------------
__global__ __launch_bounds__(256) void k_head(const float* __restrict__ x3,
                                              const float* __restrict__ wHT,
                                              const float* __restrict__ disp_b,
                                              const float* __restrict__ conf_b,
                                              const float* __restrict__ flow_up,
                                              float* __restrict__ out) {
    const int bid = blockIdx.x;
    const int b = bid & 7;
    const int t = bid >> 3;           // 0..99
    const int x0 = (t % 10) * 16, y0 = (t / 10) * 16;
    const int tx = threadIdx.x & 15, ty = threadIdx.x >> 4;
    const int tid = threadIdx.x;
    __shared__ float sh[2 * 400];  // 2 channels x 20x20
    float a0 = 0.f, a1 = 0.f, a2 = 0.f;
    const float* xb = x3 + (size_t)(b * 32) * HW;
    for (int ci = 0; ci < 32; ci += 2) {
        __syncthreads();
        for (int i = tid; i < 800; i += 256) {
            int cc = i / 400;
            int rem = i - cc * 400;
            int r = rem / 20, c2 = rem % 20;
            int gy = y0 + r - 2, gx = x0 + c2 - 2;
            float v = 0.f;
            if (gy >= 0 && gy < H && gx >= 0 && gx < W)
                v = xb[(size_t)(ci + cc) * HW + gy * W + gx];
            sh[i] = v;
        }
        __syncthreads();
#pragma unroll
        for (int cc = 0; cc < 2; ++cc) {
            const float* t2 = sh + cc * 400;
            const float* wp = wHT + (size_t)(ci + cc) * 75;
#pragma unroll
            for (int k = 0; k < 25; ++k) {
                float v = t2[(ty + k / 5) * 20 + tx + (k % 5)];
                a0 += v * wp[k * 3 + 0];
                a1 += v * wp[k * 3 + 1];
                a2 += v * wp[k * 3 + 2];
            }
        }
    }
    const int gx = x0 + tx, gy = y0 + ty;
    float d0 = a0 + disp_b[0];
    float d1 = a1 + disp_b[1];
    float cf = a2 + conf_b[0];
    cf = 1.f / (1.f + expf(-cf));

    float px = (float)gx + d0, py = (float)gy + d1;
    float x0f = floorf(px), y0f = floorf(py);
    float wx1 = px - x0f, wx0 = 1.f - wx1;
    float wy1 = py - y0f, wy0 = 1.f - wy1;
    const float* f0 = flow_up + (size_t)(b * 2) * HW;
    const float* f1 = f0 + HW;

    float m00, m01, m10, m11;
    float a00, a01, a10, a11;
    float b00, b01, b10, b11;
    auto corner = [&](float xf, float yf, float& m, float& c0, float& c1) {
        bool valid = (xf >= 0.f) && (xf <= (float)(W - 1)) && (yf >= 0.f) && (yf <= (float)(H - 1));
        m = valid ? 1.f : 0.f;
        if (valid) {
            int xi = (int)xf, yi = (int)yf;
            int o = yi * W + xi;
            c0 = f0[o]; c1 = f1[o];
        } else { c0 = 0.f; c1 = 0.f; }
    };
    corner(x0f,       y0f,       m00, a00, b00);
    corner(x0f + 1.f, y0f,       m01, a01, b01);
    corner(x0f,       y0f + 1.f, m10, a10, b10);
    corner(x0f + 1.f, y0f + 1.f, m11, a11, b11);

    float o0 = wy0 * (wx0 * a00 + wx1 * a01) + wy1 * (wx0 * a10 + wx1 * a11);
    float o1 = wy0 * (wx0 * b00 + wx1 * b01) + wy1 * (wx0 * b10 + wx1 * b11);
    float msk = wy0 * (wx0 * m00 + wx1 * m01) + wy1 * (wx0 * m10 + wx1 * m11);
    float mask = (msk >= 1.f) ? 1.f : 0.f;

    int o = gy * W + gx;
    out[(size_t)(b * 2 + 0) * HW + o] = o0 * mask;
    out[(size_t)(b * 2 + 1) * HW + o] = o1 * mask;
    out[(size_t)B * 2 * HW + (size_t)b * HW + o] = cf;
}

extern "C" void kernel_launch(void* const* d_in, const int* in_sizes, int n_in,
                              void* d_out, int out_size, void* d_ws, size_t ws_size,
                              hipStream_t stream) {
    const float* feats     = (const float*)d_in[0];
    const float* flow      = (const float*)d_in[1];
    const float* conf      = (const float*)d_in[2];
    const float* up_conf_w = (const float*)d_in[3];
    const float* up_flow_w = (const float*)d_in[4];
    const float* w1        = (const float*)d_in[5];
    const float* b1        = (const float*)d_in[6];
    const float* w2        = (const float*)d_in[7];
    const float* b2        = (const float*)d_in[8];
    const float* w3        = (const float*)d_in[9];
    const float* b3        = (const float*)d_in[10];
    const float* disp_w    = (const float*)d_in[11];
    const float* disp_b    = (const float*)d_in[12];
    const float* conf_w    = (const float*)d_in[13];
    const float* conf_b    = (const float*)d_in[14];
    float* out = (float*)d_out;

    // workspace layout (bytes)
    char* p = (char*)d_ws;
    const size_t SZ_XIN = (size_t)B * WP * WP * 128 * 2;   // 53,747,712 (hi|lo interleaved)
    const size_t SZ_X1  = (size_t)B * WP * WP * 256 * 2;   // 107,495,424
    unsigned short* xin = (unsigned short*)p;
    unsigned short* x1  = (unsigned short*)(p + SZ_XIN);
    char* p2 = p + SZ_XIN + SZ_X1;
    float* flow_up = (float*)p2;                 // 1,638,400 B
    float* wHT     = (float*)(p2 + 1638400);     // 9,600 B
    unsigned short* wpk1h = (unsigned short*)(p2 + 1648000);
    unsigned short* wpk1l = wpk1h + 73728;
    unsigned short* wpk2h = wpk1l + 73728;
    unsigned short* wpk2l = wpk2h + 73728;
    unsigned short* wpk3h = wpk2l + 73728;
    unsigned short* wpk3l = wpk3h + 18432;
    // aliases: x2 reuses xin (same geometry 2C=128, ring stays zero); x3 reuses x1
    unsigned short* x2 = xin;
    float* x3 = (float*)x1;   // 26.2 MB <= SZ_X1, x1 dead after conv2

    k_repack<<<658, 256, 0, stream>>>(w1, w2, w3, disp_w, conf_w,
                                      wpk1h, wpk1l, wpk2h, wpk2l, wpk3h, wpk3l, wHT);
    k_zeropad<<<966, 256, 0, stream>>>(xin, x1);
    // ORDER: k_corr writes each pixel's full 256-B block (ch 49 zeroed);
    // k_upsample then fills conf into ch 49. Same stream -> sequential.
    k_corr<<<800, 256, 0, stream>>>(feats, xin);
    k_upsample<<<(B * 3 * HW + 255) / 256, 256, 0, stream>>>(flow, conf, up_flow_w, up_conf_w,
                                                             flow_up, xin);
    // grids: img(8) x NCO x xh(2) x ybx(80)
    k_convM<64, 128, 4, 0><<<5120, 256, 0, stream>>>(xin, wpk1h, wpk1l, b1, x1, nullptr);
    k_convM<128, 64, 2, 0><<<2560, 256, 0, stream>>>(x1, wpk2h, wpk2l, b2, x2, nullptr);
    k_convM<64, 32, 1, 1><<<1280, 256, 0, stream>>>(x2, wpk3h, wpk3l, b3, nullptr, x3);
    k_head<<<800, 256, 0, stream>>>(x3, wHT, disp_b, conf_b, flow_up, out);
}